// Round 1
// baseline (5469.062 us; speedup 1.0000x reference)
//
#include <hip/hip_runtime.h>
#include <cstdint>
#include <cstddef>

#define D 1024
#define LSEQ 2048
#define BATCH 8

// ---------------------------------------------------------------------------
// Projection GEMM: OUT[row,col] = op( sum_k X[row,k]*W[k,col] )
// mode 0: *scale (q)   mode 1: identity (k)   mode 2: silu (v)
// 64x64 tile, BK=16, register prefetch of next tiles.
// ---------------------------------------------------------------------------
__global__ __launch_bounds__(256)
void proj_gemm(const float* __restrict__ X, const float* __restrict__ W,
               float* __restrict__ OUT, int mode, float scale) {
  __shared__ float Xs[16][68];   // [k][row], padded
  __shared__ float Ws[16][68];   // [k][col], padded
  const int tid = threadIdx.x;
  const int tx = tid & 15, ty = tid >> 4;
  const int row0 = blockIdx.y * 64, col0 = blockIdx.x * 64;

  const int lr = tid >> 2;            // 0..63 row within X tile
  const int lc = (tid & 3) * 4;       // 0,4,8,12 k-col within X tile
  const int wr = tid >> 4;            // 0..15 k-row within W tile
  const int wc = (tid & 15) * 4;      // 0..60 col within W tile

  float4 xa = *(const float4*)&X[(size_t)(row0 + lr) * D + lc];
  float4 wa = *(const float4*)&W[(size_t)wr * D + col0 + wc];

  float acc[4][4] = {{0.f}};

  for (int kt = 0; kt < D; kt += 16) {
    Xs[lc + 0][lr] = xa.x; Xs[lc + 1][lr] = xa.y;
    Xs[lc + 2][lr] = xa.z; Xs[lc + 3][lr] = xa.w;
    *(float4*)&Ws[wr][wc] = wa;
    __syncthreads();
    if (kt + 16 < D) {
      xa = *(const float4*)&X[(size_t)(row0 + lr) * D + (kt + 16) + lc];
      wa = *(const float4*)&W[(size_t)(kt + 16 + wr) * D + col0 + wc];
    }
#pragma unroll
    for (int kk = 0; kk < 16; ++kk) {
      float4 a4 = *(const float4*)&Xs[kk][ty * 4];
      float4 b4 = *(const float4*)&Ws[kk][tx * 4];
      float av[4] = {a4.x, a4.y, a4.z, a4.w};
      float bv[4] = {b4.x, b4.y, b4.z, b4.w};
#pragma unroll
      for (int i = 0; i < 4; ++i)
#pragma unroll
        for (int j = 0; j < 4; ++j) acc[i][j] += av[i] * bv[j];
    }
    __syncthreads();
  }

#pragma unroll
  for (int i = 0; i < 4; ++i) {
    float4 o4;
    float vals[4];
#pragma unroll
    for (int j = 0; j < 4; ++j) {
      float val = acc[i][j];
      if (mode == 0) val *= scale;
      else if (mode == 2) val = val / (1.f + expf(-val));   // silu
      vals[j] = val;
    }
    o4.x = vals[0]; o4.y = vals[1]; o4.z = vals[2]; o4.w = vals[3];
    *(float4*)&OUT[(size_t)(row0 + ty * 4 + i) * D + col0 + tx * 4] = o4;
  }
}

// ---------------------------------------------------------------------------
// k row L2-normalize (in place): k /= max(||k||, 1e-12). One wave per row.
// ---------------------------------------------------------------------------
__global__ __launch_bounds__(256)
void knorm_kernel(float* __restrict__ k) {
  const int lane = threadIdx.x & 63;
  const int w = threadIdx.x >> 6;
  const size_t row = (size_t)blockIdx.x * 4 + w;
  float4 vals[4];
  float ss = 0.f;
#pragma unroll
  for (int m = 0; m < 4; ++m) {
    vals[m] = *(const float4*)&k[row * D + m * 256 + lane * 4];
    ss += vals[m].x * vals[m].x + vals[m].y * vals[m].y +
          vals[m].z * vals[m].z + vals[m].w * vals[m].w;
  }
#pragma unroll
  for (int d = 1; d < 64; d <<= 1) ss += __shfl_xor(ss, d, 64);
  const float s = 1.f / fmaxf(sqrtf(ss), 1e-12f);
#pragma unroll
  for (int m = 0; m < 4; ++m) {
    float4 y;
    y.x = vals[m].x * s; y.y = vals[m].y * s;
    y.z = vals[m].z * s; y.w = vals[m].w * s;
    *(float4*)&k[row * D + m * 256 + lane * 4] = y;
  }
}

// ---------------------------------------------------------------------------
// beta[row] = sigmoid( dot(x_row, Wb) ). One wave per row.
// ---------------------------------------------------------------------------
__global__ __launch_bounds__(256)
void beta_kernel(const float* __restrict__ x, const float* __restrict__ Wb,
                 float* __restrict__ beta) {
  const int lane = threadIdx.x & 63;
  const int w = threadIdx.x >> 6;
  const size_t row = (size_t)blockIdx.x * 4 + w;
  float s = 0.f;
#pragma unroll
  for (int m = 0; m < 4; ++m) {
    float4 xv = *(const float4*)&x[row * D + m * 256 + lane * 4];
    float4 wv = *(const float4*)&Wb[m * 256 + lane * 4];
    s += xv.x * wv.x + xv.y * wv.y + xv.z * wv.z + xv.w * wv.w;
  }
#pragma unroll
  for (int d = 1; d < 64; d <<= 1) s += __shfl_xor(s, d, 64);
  if (lane == 0) beta[row] = 1.f / (1.f + expf(-s));
}

// ---------------------------------------------------------------------------
// Delta-rule scan. Grid (64 col-slices, 8 batches), 256 threads (4 waves).
// Wave owns 4 output columns; lane (c = lane>>4, g = lane&15) holds state
// rows [64g, 64g+64) of column (colbase + c) in 64 VGPRs.
// k,q rows staged in LDS per step with +4/64 swizzle (kills 16-way bank
// conflict on strided reads). Next step's operands prefetched into regs.
// ---------------------------------------------------------------------------
__global__ __launch_bounds__(256)
void scan_kernel(const float* __restrict__ q, const float* __restrict__ k,
                 const float* __restrict__ v, const float* __restrict__ beta,
                 float* __restrict__ o) {
  __shared__ float ksh[1088];
  __shared__ float qsh[1088];
  const int tid = threadIdx.x;
  const int lane = tid & 63;
  const int w = tid >> 6;
  const int b = blockIdx.y;
  const int colbase = blockIdx.x * 16 + w * 4;
  const int c = lane >> 4;
  const int g = lane & 15;
  const int col = colbase + c;
  const int kb = g * 68;                       // swizzled base of this lane's 64 rows
  const int sw = tid * 4 + ((tid >> 4) << 2);  // swizzled store offset

  float S[64];
#pragma unroll
  for (int m = 0; m < 64; ++m) S[m] = 0.f;

  const size_t base = (size_t)b * LSEQ * D;
  // prefetch t = 0
  float4 kv4 = *(const float4*)&k[base + tid * 4];
  float4 qv4 = *(const float4*)&q[base + tid * 4];
  float vc = v[base + col];
  float bt = beta[(size_t)b * LSEQ];

  for (int t = 0; t < LSEQ; ++t) {
    *(float4*)&ksh[sw] = kv4;
    *(float4*)&qsh[sw] = qv4;
    __syncthreads();
    const float vcur = vc, bcur = bt;
    if (t + 1 < LSEQ) {
      const size_t roff = base + (size_t)(t + 1) * D;
      kv4 = *(const float4*)&k[roff + tid * 4];
      qv4 = *(const float4*)&q[roff + tid * 4];
      vc = v[roff + col];
      bt = beta[(size_t)b * LSEQ + t + 1];
    }
    // Phase A: ps = sum_dk k[dk] * S[dk][col]  (partial over this lane's rows)
    float p0 = 0.f, p1 = 0.f, p2 = 0.f, p3 = 0.f;
#pragma unroll
    for (int mm = 0; mm < 16; ++mm) {
      float4 kv = *(const float4*)&ksh[kb + 4 * mm];
      p0 += kv.x * S[4 * mm + 0];
      p1 += kv.y * S[4 * mm + 1];
      p2 += kv.z * S[4 * mm + 2];
      p3 += kv.w * S[4 * mm + 3];
    }
    float ps = (p0 + p1) + (p2 + p3);
    ps += __shfl_xor(ps, 1, 64);
    ps += __shfl_xor(ps, 2, 64);
    ps += __shfl_xor(ps, 4, 64);
    ps += __shfl_xor(ps, 8, 64);
    const float u = bcur * (vcur - ps);   // v_adj for this column
    // Phase B: S += k*u (rank-1) fused with os = sum_dk q[dk]*S_new[dk][col]
    float o0 = 0.f, o1 = 0.f, o2 = 0.f, o3 = 0.f;
#pragma unroll
    for (int mm = 0; mm < 16; ++mm) {
      float4 kv = *(const float4*)&ksh[kb + 4 * mm];
      float4 qv = *(const float4*)&qsh[kb + 4 * mm];
      float s0 = S[4 * mm + 0] + kv.x * u; S[4 * mm + 0] = s0; o0 += qv.x * s0;
      float s1 = S[4 * mm + 1] + kv.y * u; S[4 * mm + 1] = s1; o1 += qv.y * s1;
      float s2 = S[4 * mm + 2] + kv.z * u; S[4 * mm + 2] = s2; o2 += qv.z * s2;
      float s3 = S[4 * mm + 3] + kv.w * u; S[4 * mm + 3] = s3; o3 += qv.w * s3;
    }
    float os = (o0 + o1) + (o2 + o3);
    os += __shfl_xor(os, 1, 64);
    os += __shfl_xor(os, 2, 64);
    os += __shfl_xor(os, 4, 64);
    os += __shfl_xor(os, 8, 64);
    if (g == 0) o[base + (size_t)t * D + col] = os;
    __syncthreads();
  }
}

// ---------------------------------------------------------------------------
// LayerNorm in place on o (d_out). One wave per row, two-pass in registers.
// ---------------------------------------------------------------------------
__global__ __launch_bounds__(256)
void ln_kernel(float* __restrict__ o, const float* __restrict__ gamma,
               const float* __restrict__ betap) {
  const int lane = threadIdx.x & 63;
  const int w = threadIdx.x >> 6;
  const size_t row = (size_t)blockIdx.x * 4 + w;
  float4 vals[4];
  float s = 0.f;
#pragma unroll
  for (int m = 0; m < 4; ++m) {
    vals[m] = *(const float4*)&o[row * D + m * 256 + lane * 4];
    s += (vals[m].x + vals[m].y) + (vals[m].z + vals[m].w);
  }
#pragma unroll
  for (int d = 1; d < 64; d <<= 1) s += __shfl_xor(s, d, 64);
  const float mu = s * (1.f / 1024.f);
  float vs = 0.f;
#pragma unroll
  for (int m = 0; m < 4; ++m) {
    float dx = vals[m].x - mu; vs += dx * dx;
    dx = vals[m].y - mu; vs += dx * dx;
    dx = vals[m].z - mu; vs += dx * dx;
    dx = vals[m].w - mu; vs += dx * dx;
  }
#pragma unroll
  for (int d = 1; d < 64; d <<= 1) vs += __shfl_xor(vs, d, 64);
  const float r = 1.f / sqrtf(vs * (1.f / 1024.f) + 1e-5f);
#pragma unroll
  for (int m = 0; m < 4; ++m) {
    const int dbase = m * 256 + lane * 4;
    float4 g4 = *(const float4*)&gamma[dbase];
    float4 b4 = *(const float4*)&betap[dbase];
    float4 y;
    y.x = (vals[m].x - mu) * r * g4.x + b4.x;
    y.y = (vals[m].y - mu) * r * g4.y + b4.y;
    y.z = (vals[m].z - mu) * r * g4.z + b4.z;
    y.w = (vals[m].w - mu) * r * g4.w + b4.w;
    *(float4*)&o[row * D + dbase] = y;
  }
}

// ---------------------------------------------------------------------------
extern "C" void kernel_launch(void* const* d_in, const int* in_sizes, int n_in,
                              void* d_out, int out_size, void* d_ws, size_t ws_size,
                              hipStream_t stream) {
  const float* x   = (const float*)d_in[0];
  const float* Wq  = (const float*)d_in[1];
  const float* Wk  = (const float*)d_in[2];
  const float* Wv  = (const float*)d_in[3];
  const float* Wb  = (const float*)d_in[4];
  const float* lng = (const float*)d_in[5];
  const float* lnb = (const float*)d_in[6];
  float* out = (float*)d_out;

  const size_t N = (size_t)BATCH * LSEQ * D;   // 16,777,216
  float* q    = (float*)d_ws;
  float* k    = q + N;
  float* v    = k + N;
  float* beta = v + N;   // B*L floats

  dim3 gg(16, 256);
  proj_gemm<<<gg, 256, 0, stream>>>(x, Wq, q, 0, 0.03125f);  // q = xWq * D^-0.5
  proj_gemm<<<gg, 256, 0, stream>>>(x, Wk, k, 1, 1.f);       // k = xWk
  proj_gemm<<<gg, 256, 0, stream>>>(x, Wv, v, 2, 1.f);       // v = silu(xWv)
  knorm_kernel<<<4096, 256, 0, stream>>>(k);
  beta_kernel<<<4096, 256, 0, stream>>>(x, Wb, beta);
  scan_kernel<<<dim3(64, 8), 256, 0, stream>>>(q, k, v, beta, out);
  ln_kernel<<<4096, 256, 0, stream>>>(out, lng, lnb);
}

// Round 2
// 2303.086 us; speedup vs baseline: 2.3747x; 2.3747x over previous
//
#include <hip/hip_runtime.h>
#include <cstdint>
#include <cstddef>

#define D 1024
#define LSEQ 2048
#define BATCH 8
#define NCHUNK 32   // LSEQ / 64

typedef float fx4  __attribute__((ext_vector_type(4)));
typedef short s16x8 __attribute__((ext_vector_type(8)));
typedef short s16x4 __attribute__((ext_vector_type(4)));

static __device__ __forceinline__ short f2bf(float f) {
  unsigned u = __builtin_bit_cast(unsigned, f);
  u = (u + 0x7FFFu + ((u >> 16) & 1u)) >> 16;   // RNE (finite values)
  return (short)u;
}
static __device__ __forceinline__ float bf2f(unsigned short h) {
  unsigned u = ((unsigned)h) << 16;
  return __builtin_bit_cast(float, u);
}

// ---------------------------------------------------------------------------
// Projection GEMM (fp32): OUT[row,col] = op( sum_k X[row,k]*W[k,col] )
// mode 0: *scale (q)   mode 1: identity (k)   mode 2: silu (v)
// ---------------------------------------------------------------------------
__global__ __launch_bounds__(256)
void proj_gemm(const float* __restrict__ X, const float* __restrict__ W,
               float* __restrict__ OUT, int mode, float scale) {
  __shared__ float Xs[16][68];
  __shared__ float Ws[16][68];
  const int tid = threadIdx.x;
  const int tx = tid & 15, ty = tid >> 4;
  const int row0 = blockIdx.y * 64, col0 = blockIdx.x * 64;
  const int lr = tid >> 2;
  const int lc = (tid & 3) * 4;
  const int wr = tid >> 4;
  const int wc = (tid & 15) * 4;

  float4 xa = *(const float4*)&X[(size_t)(row0 + lr) * D + lc];
  float4 wa = *(const float4*)&W[(size_t)wr * D + col0 + wc];
  float acc[4][4] = {{0.f}};

  for (int kt = 0; kt < D; kt += 16) {
    Xs[lc + 0][lr] = xa.x; Xs[lc + 1][lr] = xa.y;
    Xs[lc + 2][lr] = xa.z; Xs[lc + 3][lr] = xa.w;
    *(float4*)&Ws[wr][wc] = wa;
    __syncthreads();
    if (kt + 16 < D) {
      xa = *(const float4*)&X[(size_t)(row0 + lr) * D + (kt + 16) + lc];
      wa = *(const float4*)&W[(size_t)(kt + 16 + wr) * D + col0 + wc];
    }
#pragma unroll
    for (int kk = 0; kk < 16; ++kk) {
      float4 a4 = *(const float4*)&Xs[kk][ty * 4];
      float4 b4 = *(const float4*)&Ws[kk][tx * 4];
      float av[4] = {a4.x, a4.y, a4.z, a4.w};
      float bv[4] = {b4.x, b4.y, b4.z, b4.w};
#pragma unroll
      for (int i = 0; i < 4; ++i)
#pragma unroll
        for (int j = 0; j < 4; ++j) acc[i][j] += av[i] * bv[j];
    }
    __syncthreads();
  }
#pragma unroll
  for (int i = 0; i < 4; ++i) {
    float vals[4];
#pragma unroll
    for (int j = 0; j < 4; ++j) {
      float val = acc[i][j];
      if (mode == 0) val *= scale;
      else if (mode == 2) val = val / (1.f + expf(-val));
      vals[j] = val;
    }
    float4 o4 = {vals[0], vals[1], vals[2], vals[3]};
    *(float4*)&OUT[(size_t)(row0 + ty * 4 + i) * D + col0 + tx * 4] = o4;
  }
}

// ---------------------------------------------------------------------------
// pack fp32 -> bf16 (grid-stride, 8 elems/thread/iter)
// ---------------------------------------------------------------------------
__global__ __launch_bounds__(256)
void pack_bf16(const float* __restrict__ in, short* __restrict__ outp, int n8) {
  int i = blockIdx.x * 256 + threadIdx.x;
  const int stride = gridDim.x * 256;
  for (; i < n8; i += stride) {
    const float* p = in + (size_t)i * 8;
    s16x8 o;
#pragma unroll
    for (int j = 0; j < 8; ++j) o[j] = f2bf(p[j]);
    *(s16x8*)(outp + (size_t)i * 8) = o;
  }
}

// ---------------------------------------------------------------------------
// k row L2-normalize fp32 -> bf16. One wave per row.
// ---------------------------------------------------------------------------
__global__ __launch_bounds__(256)
void knorm_bf16(const float* __restrict__ kin, short* __restrict__ kout) {
  const int lane = threadIdx.x & 63;
  const int w = threadIdx.x >> 6;
  const size_t row = (size_t)blockIdx.x * 4 + w;
  float4 vals[4];
  float ss = 0.f;
#pragma unroll
  for (int m = 0; m < 4; ++m) {
    vals[m] = *(const float4*)&kin[row * D + m * 256 + lane * 4];
    ss += vals[m].x * vals[m].x + vals[m].y * vals[m].y +
          vals[m].z * vals[m].z + vals[m].w * vals[m].w;
  }
#pragma unroll
  for (int d = 1; d < 64; d <<= 1) ss += __shfl_xor(ss, d, 64);
  const float s = 1.f / fmaxf(sqrtf(ss), 1e-12f);
#pragma unroll
  for (int m = 0; m < 4; ++m) {
    s16x4 y;
    y[0] = f2bf(vals[m].x * s); y[1] = f2bf(vals[m].y * s);
    y[2] = f2bf(vals[m].z * s); y[3] = f2bf(vals[m].w * s);
    *(s16x4*)(kout + row * D + m * 256 + lane * 4) = y;
  }
}

// ---------------------------------------------------------------------------
// transpose kh [b][L][D] -> kT [b][D][L] (bf16), 64x64 tiles via LDS
// ---------------------------------------------------------------------------
__global__ __launch_bounds__(256)
void transpose_bf16(const short* __restrict__ kh, short* __restrict__ kT) {
  __shared__ short Tl[64][66];
  const int dt = blockIdx.x, lt = blockIdx.y, b = blockIdx.z;
  const int tid = threadIdx.x;
  const int c = (tid & 15) * 4, r = tid >> 4;
#pragma unroll
  for (int p = 0; p < 4; ++p) {
    const int row = r + p * 16;
    s16x4 v4 = *(const s16x4*)(kh + ((size_t)b * LSEQ + lt * 64 + row) * D + dt * 64 + c);
#pragma unroll
    for (int j = 0; j < 4; ++j) Tl[c + j][row] = v4[j];
  }
  __syncthreads();
#pragma unroll
  for (int p = 0; p < 4; ++p) {
    const int dk = r + p * 16;
    s16x4 o4;
#pragma unroll
    for (int j = 0; j < 4; ++j) o4[j] = Tl[dk][c + j];
    *(s16x4*)(kT + ((size_t)b * D + dt * 64 + dk) * LSEQ + lt * 64 + c) = o4;
  }
}

// ---------------------------------------------------------------------------
// beta[row] = sigmoid( dot(x_row, Wb) ). fp32 exact.
// ---------------------------------------------------------------------------
__global__ __launch_bounds__(256)
void beta_kernel(const float* __restrict__ x, const float* __restrict__ Wb,
                 float* __restrict__ beta) {
  const int lane = threadIdx.x & 63;
  const int w = threadIdx.x >> 6;
  const size_t row = (size_t)blockIdx.x * 4 + w;
  float s = 0.f;
#pragma unroll
  for (int m = 0; m < 4; ++m) {
    float4 xv = *(const float4*)&x[row * D + m * 256 + lane * 4];
    float4 wv = *(const float4*)&Wb[m * 256 + lane * 4];
    s += xv.x * wv.x + xv.y * wv.y + xv.z * wv.z + xv.w * wv.w;
  }
#pragma unroll
  for (int d = 1; d < 64; d <<= 1) s += __shfl_xor(s, d, 64);
  if (lane == 0) beta[row] = 1.f / (1.f + expf(-s));
}

// ---------------------------------------------------------------------------
// Precompute per chunk (b,t): Minv = (I + beta*tril(K K^T,-1))^{-1} (bf16)
// and Tg = tril(Q K^T, 0) (bf16). One block per chunk, 4 waves, MFMA.
// ---------------------------------------------------------------------------
__global__ __launch_bounds__(256)
void precompute(const short* __restrict__ qh, const short* __restrict__ kh,
                const float* __restrict__ beta,
                short* __restrict__ Mg, short* __restrict__ Tg) {
  __shared__ float Ash[64 * 65];
  __shared__ float Msh[64 * 65];
  const int tid = threadIdx.x, l = tid & 63, w = tid >> 6;
  const int bt = blockIdx.x;
  const int b = bt >> 5, t = bt & 31;
  const int lo = l & 15, hi = l >> 4;
  const size_t rb = (size_t)b * LSEQ + t * 64;

  fx4 aK[4], aQ[4];
#pragma unroll
  for (int n = 0; n < 4; ++n) { aK[n] = (fx4){0,0,0,0}; aQ[n] = (fx4){0,0,0,0}; }

  const short* krow = kh + (rb + w * 16 + lo) * D;
  const short* qrow = qh + (rb + w * 16 + lo) * D;
#pragma unroll 2
  for (int ks = 0; ks < 32; ++ks) {
    s16x8 ak = *(const s16x8*)(krow + ks * 32 + hi * 8);
    s16x8 aq = *(const s16x8*)(qrow + ks * 32 + hi * 8);
#pragma unroll
    for (int n = 0; n < 4; ++n) {
      s16x8 bk = *(const s16x8*)(kh + (rb + n * 16 + lo) * D + ks * 32 + hi * 8);
      aK[n] = __builtin_amdgcn_mfma_f32_16x16x32_bf16(ak, bk, aK[n], 0, 0, 0);
      aQ[n] = __builtin_amdgcn_mfma_f32_16x16x32_bf16(aq, bk, aQ[n], 0, 0, 0);
    }
  }
  // A = beta_i * strict-lower(KK^T);  Tg = lower-incl-diag(QK^T)
#pragma unroll
  for (int n = 0; n < 4; ++n) {
#pragma unroll
    for (int r = 0; r < 4; ++r) {
      const int i = w * 16 + hi * 4 + r, s = n * 16 + lo;
      const float bi = beta[rb + i];
      Ash[i * 65 + s] = (s < i) ? bi * aK[n][r] : 0.f;
      Tg[(size_t)bt * 4096 + i * 64 + s] = (s <= i) ? f2bf(aQ[n][r]) : (short)0;
    }
  }
  __syncthreads();
  // forward substitution: Minv[i][:] = e_i - sum_{s<i} A[i][s] Minv[s][:]
  if (w == 0) {
    Msh[0 * 65 + l] = (l == 0) ? 1.f : 0.f;
    for (int i = 1; i < 64; ++i) {
      float s = 0.f;
      for (int ss = 0; ss < i; ++ss) s += Ash[i * 65 + ss] * Msh[ss * 65 + l];
      Msh[i * 65 + l] = ((i == l) ? 1.f : 0.f) - s;
    }
  }
  __syncthreads();
  {
    const int row = tid >> 2, c0 = (tid & 3) * 16;
    s16x8 o0, o1;
#pragma unroll
    for (int j = 0; j < 8; ++j) o0[j] = f2bf(Msh[row * 65 + c0 + j]);
#pragma unroll
    for (int j = 0; j < 8; ++j) o1[j] = f2bf(Msh[row * 65 + c0 + 8 + j]);
    *(s16x8*)(Mg + (size_t)bt * 4096 + row * 64 + c0) = o0;
    *(s16x8*)(Mg + (size_t)bt * 4096 + row * 64 + c0 + 8) = o1;
  }
}

// ---------------------------------------------------------------------------
// Sequential chunked scan. Grid (32 n-slices, 8 batches), 512 threads (8 waves).
// S [1024dk x 32n] fp32 lives in MFMA accumulators (16 frags/wave, wave w owns
// dk in [w*128, w*128+128)). Per chunk:
//   P1: R = K_c @ S      (B-frags from swizzled bf16 SB in LDS)
//   rhs = beta*(V - R) -> rhsT (LDS, bf16, [n][c] k-contig)
//   P2: U = Minv @ rhs -> UT (LDS)
//   P3: O = Q_c @ S + trilQK @ U -> global fp32
//   P4: S += K_c^T @ U   (A-frags from global kT, accumulate into S regs)
//   P5: refresh SB = bf16(S)
// All LDS buffers XOR-swizzled: byte ^= (row&7)<<4  (kills 16-way conflicts).
// ---------------------------------------------------------------------------
__global__ __launch_bounds__(512)
void scan_chunked(const short* __restrict__ qh, const short* __restrict__ kh,
                  const short* __restrict__ vh, const short* __restrict__ kT,
                  const float* __restrict__ beta,
                  const short* __restrict__ Mg, const short* __restrict__ Tg,
                  float* __restrict__ out) {
  __shared__ short SBs[32 * 1024];   // S operand, [n][dk] bf16 swizzled
  __shared__ short RTs[32 * 64];     // rhsT [n][c]
  __shared__ short UTs[32 * 64];     // UT  [n][c]
  const int tid = threadIdx.x;
  const int l = tid & 63, w = tid >> 6;
  const int b = blockIdx.y, n0 = blockIdx.x * 32;
  const int lo = l & 15, hi = l >> 4;
  const int mR = w >> 1, nR = w & 1;         // job for P1/P2/P3
  const size_t bL = (size_t)b * LSEQ;

  // zero SB (chunk 0: S = 0)
  for (int i = tid; i < 32 * 1024 / 2; i += 512) ((int*)SBs)[i] = 0;
  __syncthreads();

  fx4 S[8][2];
#pragma unroll
  for (int mt = 0; mt < 8; ++mt)
#pragma unroll
    for (int nt = 0; nt < 2; ++nt) S[mt][nt] = (fx4){0, 0, 0, 0};

  const int nl = nR * 16 + lo;       // local col for P1/P2/P3
  const int c0 = mR * 16 + hi * 4;   // local row base
  const int swn = (nl & 7) << 4;

  for (int t = 0; t < NCHUNK; ++t) {
    const int r0 = t * 64;
    // ---- P1: R = K_c @ S
    fx4 acc = (fx4){0, 0, 0, 0};
    {
      const short* Arow = kh + (bL + r0 + mR * 16 + lo) * D;
#pragma unroll 4
      for (int ks = 0; ks < 32; ++ks) {
        s16x8 a = *(const s16x8*)(Arow + ks * 32 + hi * 8);
        s16x8 bf = *(const s16x8*)((char*)SBs + (size_t)nl * 2048 +
                                   (((ks * 32 + hi * 8) * 2) ^ swn));
        acc = __builtin_amdgcn_mfma_f32_16x16x32_bf16(a, bf, acc, 0, 0, 0);
      }
    }
    {
      s16x4 pk;
#pragma unroll
      for (int r = 0; r < 4; ++r) {
        const float bv = beta[bL + r0 + c0 + r];
        const float vv = bf2f(((const unsigned short*)vh)[(bL + r0 + c0 + r) * D + n0 + nl]);
        pk[r] = f2bf(bv * (vv - acc[r]));
      }
      *(s16x4*)((char*)RTs + nl * 128 + ((c0 * 2) ^ swn)) = pk;
    }
    __syncthreads();
    // ---- P2: U = Minv @ rhs
    acc = (fx4){0, 0, 0, 0};
    {
      const short* Mrow = Mg + ((size_t)(b * NCHUNK + t)) * 4096 + (mR * 16 + lo) * 64;
#pragma unroll
      for (int ks = 0; ks < 2; ++ks) {
        s16x8 a = *(const s16x8*)(Mrow + ks * 32 + hi * 8);
        s16x8 bf = *(const s16x8*)((char*)RTs + nl * 128 +
                                   (((ks * 32 + hi * 8) * 2) ^ swn));
        acc = __builtin_amdgcn_mfma_f32_16x16x32_bf16(a, bf, acc, 0, 0, 0);
      }
      s16x4 pk;
#pragma unroll
      for (int r = 0; r < 4; ++r) pk[r] = f2bf(acc[r]);
      *(s16x4*)((char*)UTs + nl * 128 + ((c0 * 2) ^ swn)) = pk;
    }
    __syncthreads();
    // ---- P3: O = Q_c @ S + trilQK @ U
    acc = (fx4){0, 0, 0, 0};
    {
      const short* Qrow = qh + (bL + r0 + mR * 16 + lo) * D;
#pragma unroll 4
      for (int ks = 0; ks < 32; ++ks) {
        s16x8 a = *(const s16x8*)(Qrow + ks * 32 + hi * 8);
        s16x8 bf = *(const s16x8*)((char*)SBs + (size_t)nl * 2048 +
                                   (((ks * 32 + hi * 8) * 2) ^ swn));
        acc = __builtin_amdgcn_mfma_f32_16x16x32_bf16(a, bf, acc, 0, 0, 0);
      }
      const short* Trow = Tg + ((size_t)(b * NCHUNK + t)) * 4096 + (mR * 16 + lo) * 64;
#pragma unroll
      for (int ks = 0; ks < 2; ++ks) {
        s16x8 a = *(const s16x8*)(Trow + ks * 32 + hi * 8);
        s16x8 bf = *(const s16x8*)((char*)UTs + nl * 128 +
                                   (((ks * 32 + hi * 8) * 2) ^ swn));
        acc = __builtin_amdgcn_mfma_f32_16x16x32_bf16(a, bf, acc, 0, 0, 0);
      }
#pragma unroll
      for (int r = 0; r < 4; ++r)
        out[(bL + r0 + c0 + r) * D + n0 + nl] = acc[r];
    }
    // ---- P4: S += K_c^T @ U  (A from global kT, B from UTs)
    {
      s16x8 Bf[2][2];
#pragma unroll
      for (int nt = 0; nt < 2; ++nt) {
        const int nn = nt * 16 + lo;
#pragma unroll
        for (int ks = 0; ks < 2; ++ks)
          Bf[nt][ks] = *(const s16x8*)((char*)UTs + nn * 128 +
                                       (((ks * 32 + hi * 8) * 2) ^ ((nn & 7) << 4)));
      }
#pragma unroll
      for (int mt = 0; mt < 8; ++mt) {
        const short* KTrow = kT + ((size_t)b * D + (w * 8 + mt) * 16 + lo) * LSEQ + r0;
#pragma unroll
        for (int ks = 0; ks < 2; ++ks) {
          s16x8 a = *(const s16x8*)(KTrow + ks * 32 + hi * 8);
#pragma unroll
          for (int nt = 0; nt < 2; ++nt)
            S[mt][nt] = __builtin_amdgcn_mfma_f32_16x16x32_bf16(a, Bf[nt][ks], S[mt][nt], 0, 0, 0);
        }
      }
    }
    __syncthreads();   // all SB reads (P1/P3) and UT reads (P4) done
    // ---- P5: SB refresh = bf16(S)
#pragma unroll
    for (int mt = 0; mt < 8; ++mt)
#pragma unroll
      for (int nt = 0; nt < 2; ++nt) {
        const int nn = nt * 16 + lo;
        const int dk0 = (w * 8 + mt) * 16 + hi * 4;
        s16x4 pk;
#pragma unroll
        for (int r = 0; r < 4; ++r) pk[r] = f2bf(S[mt][nt][r]);
        *(s16x4*)((char*)SBs + (size_t)nn * 2048 + ((dk0 * 2) ^ ((nn & 7) << 4))) = pk;
      }
    __syncthreads();
  }
}

// ---------------------------------------------------------------------------
// LayerNorm in place on out. One wave per row.
// ---------------------------------------------------------------------------
__global__ __launch_bounds__(256)
void ln_kernel(float* __restrict__ o, const float* __restrict__ gamma,
               const float* __restrict__ betap) {
  const int lane = threadIdx.x & 63;
  const int w = threadIdx.x >> 6;
  const size_t row = (size_t)blockIdx.x * 4 + w;
  float4 vals[4];
  float s = 0.f;
#pragma unroll
  for (int m = 0; m < 4; ++m) {
    vals[m] = *(const float4*)&o[row * D + m * 256 + lane * 4];
    s += (vals[m].x + vals[m].y) + (vals[m].z + vals[m].w);
  }
#pragma unroll
  for (int d = 1; d < 64; d <<= 1) s += __shfl_xor(s, d, 64);
  const float mu = s * (1.f / 1024.f);
  float vs = 0.f;
#pragma unroll
  for (int m = 0; m < 4; ++m) {
    float dx = vals[m].x - mu; vs += dx * dx;
    dx = vals[m].y - mu; vs += dx * dx;
    dx = vals[m].z - mu; vs += dx * dx;
    dx = vals[m].w - mu; vs += dx * dx;
  }
#pragma unroll
  for (int d = 1; d < 64; d <<= 1) vs += __shfl_xor(vs, d, 64);
  const float r = 1.f / sqrtf(vs * (1.f / 1024.f) + 1e-5f);
#pragma unroll
  for (int m = 0; m < 4; ++m) {
    const int dbase = m * 256 + lane * 4;
    float4 g4 = *(const float4*)&gamma[dbase];
    float4 b4 = *(const float4*)&betap[dbase];
    float4 y;
    y.x = (vals[m].x - mu) * r * g4.x + b4.x;
    y.y = (vals[m].y - mu) * r * g4.y + b4.y;
    y.z = (vals[m].z - mu) * r * g4.z + b4.z;
    y.w = (vals[m].w - mu) * r * g4.w + b4.w;
    *(float4*)&o[row * D + dbase] = y;
  }
}

// ---------------------------------------------------------------------------
extern "C" void kernel_launch(void* const* d_in, const int* in_sizes, int n_in,
                              void* d_out, int out_size, void* d_ws, size_t ws_size,
                              hipStream_t stream) {
  const float* x   = (const float*)d_in[0];
  const float* Wq  = (const float*)d_in[1];
  const float* Wk  = (const float*)d_in[2];
  const float* Wv  = (const float*)d_in[3];
  const float* Wb  = (const float*)d_in[4];
  const float* lng = (const float*)d_in[5];
  const float* lnb = (const float*)d_in[6];
  float* out = (float*)d_out;

  const size_t MB = 1ull << 20;
  char* wsb = (char*)d_ws;
  float* f0   = (float*)wsb;                 // 64 MB fp32 scratch
  short* qh   = (short*)(wsb + 64 * MB);     // 32 MB bf16
  short* kh   = (short*)(wsb + 96 * MB);
  short* vh   = (short*)(wsb + 128 * MB);
  short* kT   = (short*)(wsb + 160 * MB);
  // f0 region reused after last pack:
  float* beta = (float*)wsb;                 // 64 KB
  short* Mg   = (short*)(wsb + 1 * MB);      // 2 MB
  short* Tg   = (short*)(wsb + 4 * MB);      // 2 MB

  const int N8 = (BATCH * LSEQ * D) / 8;
  dim3 gg(16, 256);

  proj_gemm<<<gg, 256, 0, stream>>>(x, Wq, f0, 0, 0.03125f);
  pack_bf16<<<2048, 256, 0, stream>>>(f0, qh, N8);

  proj_gemm<<<gg, 256, 0, stream>>>(x, Wk, f0, 1, 1.f);
  knorm_bf16<<<4096, 256, 0, stream>>>(f0, kh);
  transpose_bf16<<<dim3(16, 32, 8), 256, 0, stream>>>(kh, kT);

  proj_gemm<<<gg, 256, 0, stream>>>(x, Wv, f0, 2, 1.f);
  pack_bf16<<<2048, 256, 0, stream>>>(f0, vh, N8);

  beta_kernel<<<4096, 256, 0, stream>>>(x, Wb, beta);
  precompute<<<256, 256, 0, stream>>>(qh, kh, beta, Mg, Tg);
  scan_chunked<<<dim3(32, 8), 512, 0, stream>>>(qh, kh, vh, kT, beta, Mg, Tg, out);
  ln_kernel<<<4096, 256, 0, stream>>>(out, lng, lnb);
}

// Round 3
// 1068.555 us; speedup vs baseline: 5.1182x; 2.1553x over previous
//
#include <hip/hip_runtime.h>
#include <cstdint>
#include <cstddef>

#define D 1024
#define LSEQ 2048
#define BATCH 8
#define NCHUNK 32   // LSEQ / 64

typedef float fx4  __attribute__((ext_vector_type(4)));
typedef short s16x8 __attribute__((ext_vector_type(8)));
typedef short s16x4 __attribute__((ext_vector_type(4)));

static __device__ __forceinline__ short f2bf(float f) {
  unsigned u = __builtin_bit_cast(unsigned, f);
  u = (u + 0x7FFFu + ((u >> 16) & 1u)) >> 16;   // RNE (finite values)
  return (short)u;
}
static __device__ __forceinline__ float bf2f(unsigned short h) {
  unsigned u = ((unsigned)h) << 16;
  return __builtin_bit_cast(float, u);
}

// ---------------------------------------------------------------------------
// pack fp32 -> bf16 (grid-stride, 8 elems/thread/iter)
// ---------------------------------------------------------------------------
__global__ __launch_bounds__(256)
void pack_bf16(const float* __restrict__ in, short* __restrict__ outp, int n8) {
  int i = blockIdx.x * 256 + threadIdx.x;
  const int stride = gridDim.x * 256;
  for (; i < n8; i += stride) {
    const float* p = in + (size_t)i * 8;
    s16x8 o;
#pragma unroll
    for (int j = 0; j < 8; ++j) o[j] = f2bf(p[j]);
    *(s16x8*)(outp + (size_t)i * 8) = o;
  }
}

// ---------------------------------------------------------------------------
// W [K][N] fp32 -> WT [N][K] bf16, 64x64 tiles via LDS
// ---------------------------------------------------------------------------
__global__ __launch_bounds__(256)
void wtrans(const float* __restrict__ W, short* __restrict__ WT) {
  __shared__ short Tl[64][66];
  const int nt = blockIdx.x, kt0 = blockIdx.y;
  const int tid = threadIdx.x;
  const int c = (tid & 15) * 4, r = tid >> 4;
#pragma unroll
  for (int p = 0; p < 4; ++p) {
    const int krow = r + p * 16;
    float4 v4 = *(const float4*)&W[(size_t)(kt0 * 64 + krow) * D + nt * 64 + c];
    Tl[c + 0][krow] = f2bf(v4.x);
    Tl[c + 1][krow] = f2bf(v4.y);
    Tl[c + 2][krow] = f2bf(v4.z);
    Tl[c + 3][krow] = f2bf(v4.w);
  }
  __syncthreads();
#pragma unroll
  for (int p = 0; p < 4; ++p) {
    const int n = r + p * 16;
    s16x4 o4;
#pragma unroll
    for (int j = 0; j < 4; ++j) o4[j] = Tl[n][c + j];
    *(s16x4*)(WT + (size_t)(nt * 64 + n) * D + kt0 * 64 + c) = o4;
  }
}

// ---------------------------------------------------------------------------
// bf16 MFMA projection GEMM: OUT[m][n] = op( sum_k A[m][k] * Bt[n][k] )
// 128x128 tile, BK=32, 4 waves (2x2 of 64x64), double-buffered LDS staged
// via global_load_lds width=16. LDS layout: chunk (hi, m) of 8 bf16 at
// index (hi*128+m)*8 -> fragment ds_read_b128 conflict-free.
// mode 0: *scale (q)   mode 1: identity (k)   mode 2: silu (v)
// ---------------------------------------------------------------------------
__global__ __launch_bounds__(256)
void proj_mfma(const short* __restrict__ A, const short* __restrict__ Bt,
               short* __restrict__ OUT, int mode, float scale) {
  __shared__ short As[2][4096];
  __shared__ short Bs[2][4096];
  const int tid = threadIdx.x;
  const int l = tid & 63, w = tid >> 6;
  const int lo = l & 15, hi = l >> 4;
  const int wm = w >> 1, wn = w & 1;
  const int row0 = blockIdx.x * 128, col0 = blockIdx.y * 128;

#define STAGE(nb, ktn)                                                          \
  {                                                                             \
    const short* ga0 = A + ((size_t)(row0 + l) * D + (ktn) + w * 8);            \
    const short* gb0 = Bt + ((size_t)(col0 + l) * D + (ktn) + w * 8);           \
    __builtin_amdgcn_global_load_lds(                                           \
        (const __attribute__((address_space(1))) void*)ga0,                     \
        (__attribute__((address_space(3))) void*)&As[nb][(w * 128) * 8], 16, 0, 0); \
    __builtin_amdgcn_global_load_lds(                                           \
        (const __attribute__((address_space(1))) void*)(ga0 + 64 * D),          \
        (__attribute__((address_space(3))) void*)&As[nb][(w * 128 + 64) * 8], 16, 0, 0); \
    __builtin_amdgcn_global_load_lds(                                           \
        (const __attribute__((address_space(1))) void*)gb0,                     \
        (__attribute__((address_space(3))) void*)&Bs[nb][(w * 128) * 8], 16, 0, 0); \
    __builtin_amdgcn_global_load_lds(                                           \
        (const __attribute__((address_space(1))) void*)(gb0 + 64 * D),          \
        (__attribute__((address_space(3))) void*)&Bs[nb][(w * 128 + 64) * 8], 16, 0, 0); \
  }

  fx4 acc[4][4];
#pragma unroll
  for (int i = 0; i < 4; ++i)
#pragma unroll
    for (int j = 0; j < 4; ++j) acc[i][j] = (fx4){0.f, 0.f, 0.f, 0.f};

  STAGE(0, 0);
  __syncthreads();
  int cur = 0;
  for (int kt = 0; kt < D; kt += 32) {
    if (kt + 32 < D) STAGE(cur ^ 1, kt + 32);
    s16x8 af[4], bfr[4];
#pragma unroll
    for (int mt = 0; mt < 4; ++mt)
      af[mt] = *(const s16x8*)&As[cur][(hi * 128 + wm * 64 + mt * 16 + lo) * 8];
#pragma unroll
    for (int nt = 0; nt < 4; ++nt)
      bfr[nt] = *(const s16x8*)&Bs[cur][(hi * 128 + wn * 64 + nt * 16 + lo) * 8];
#pragma unroll
    for (int mt = 0; mt < 4; ++mt)
#pragma unroll
      for (int nt = 0; nt < 4; ++nt)
        acc[mt][nt] = __builtin_amdgcn_mfma_f32_16x16x32_bf16(af[mt], bfr[nt], acc[mt][nt], 0, 0, 0);
    __syncthreads();
    cur ^= 1;
  }
#undef STAGE

#pragma unroll
  for (int mt = 0; mt < 4; ++mt)
#pragma unroll
    for (int nt = 0; nt < 4; ++nt) {
      const size_t rbase = (size_t)(row0 + wm * 64 + mt * 16 + hi * 4);
      const int col = col0 + wn * 64 + nt * 16 + lo;
#pragma unroll
      for (int r = 0; r < 4; ++r) {
        float val = acc[mt][nt][r];
        if (mode == 0) val *= scale;
        else if (mode == 2) val = val / (1.f + expf(-val));
        OUT[(rbase + r) * D + col] = f2bf(val);
      }
    }
}

// ---------------------------------------------------------------------------
// k row L2-normalize, bf16 in place. One wave per row.
// ---------------------------------------------------------------------------
__global__ __launch_bounds__(256)
void knormb(short* __restrict__ kk) {
  const int lane = threadIdx.x & 63;
  const int w = threadIdx.x >> 6;
  const size_t row = (size_t)blockIdx.x * 4 + w;
  s16x8 v0 = *(const s16x8*)&kk[row * D + lane * 8];
  s16x8 v1 = *(const s16x8*)&kk[row * D + 512 + lane * 8];
  float f[16];
  float ss = 0.f;
#pragma unroll
  for (int j = 0; j < 8; ++j) {
    f[j] = bf2f((unsigned short)v0[j]);
    f[8 + j] = bf2f((unsigned short)v1[j]);
  }
#pragma unroll
  for (int j = 0; j < 16; ++j) ss += f[j] * f[j];
#pragma unroll
  for (int d = 1; d < 64; d <<= 1) ss += __shfl_xor(ss, d, 64);
  const float s = 1.f / fmaxf(sqrtf(ss), 1e-12f);
  s16x8 o0, o1;
#pragma unroll
  for (int j = 0; j < 8; ++j) {
    o0[j] = f2bf(f[j] * s);
    o1[j] = f2bf(f[8 + j] * s);
  }
  *(s16x8*)&kk[row * D + lane * 8] = o0;
  *(s16x8*)&kk[row * D + 512 + lane * 8] = o1;
}

// ---------------------------------------------------------------------------
// transpose kh [b][L][D] -> kT [b][D][L] (bf16), 64x64 tiles via LDS
// ---------------------------------------------------------------------------
__global__ __launch_bounds__(256)
void transpose_bf16(const short* __restrict__ kh, short* __restrict__ kT) {
  __shared__ short Tl[64][66];
  const int dt = blockIdx.x, lt = blockIdx.y, b = blockIdx.z;
  const int tid = threadIdx.x;
  const int c = (tid & 15) * 4, r = tid >> 4;
#pragma unroll
  for (int p = 0; p < 4; ++p) {
    const int row = r + p * 16;
    s16x4 v4 = *(const s16x4*)(kh + ((size_t)b * LSEQ + lt * 64 + row) * D + dt * 64 + c);
#pragma unroll
    for (int j = 0; j < 4; ++j) Tl[c + j][row] = v4[j];
  }
  __syncthreads();
#pragma unroll
  for (int p = 0; p < 4; ++p) {
    const int dk = r + p * 16;
    s16x4 o4;
#pragma unroll
    for (int j = 0; j < 4; ++j) o4[j] = Tl[dk][c + j];
    *(s16x4*)(kT + ((size_t)b * D + dt * 64 + dk) * LSEQ + lt * 64 + c) = o4;
  }
}

// ---------------------------------------------------------------------------
// beta[row] = sigmoid( dot(x_row, Wb) ). fp32 exact.
// ---------------------------------------------------------------------------
__global__ __launch_bounds__(256)
void beta_kernel(const float* __restrict__ x, const float* __restrict__ Wb,
                 float* __restrict__ beta) {
  const int lane = threadIdx.x & 63;
  const int w = threadIdx.x >> 6;
  const size_t row = (size_t)blockIdx.x * 4 + w;
  float s = 0.f;
#pragma unroll
  for (int m = 0; m < 4; ++m) {
    float4 xv = *(const float4*)&x[row * D + m * 256 + lane * 4];
    float4 wv = *(const float4*)&Wb[m * 256 + lane * 4];
    s += xv.x * wv.x + xv.y * wv.y + xv.z * wv.z + xv.w * wv.w;
  }
#pragma unroll
  for (int d = 1; d < 64; d <<= 1) s += __shfl_xor(s, d, 64);
  if (lane == 0) beta[row] = 1.f / (1.f + expf(-s));
}

// ---------------------------------------------------------------------------
// Precompute per chunk (b,t): Minv = (I + beta*tril(K K^T,-1))^{-1} (bf16)
// and Tg = tril(Q K^T, 0) (bf16). One block per chunk, 4 waves, MFMA.
// ---------------------------------------------------------------------------
__global__ __launch_bounds__(256)
void precompute(const short* __restrict__ qh, const short* __restrict__ kh,
                const float* __restrict__ beta,
                short* __restrict__ Mg, short* __restrict__ Tg) {
  __shared__ float Ash[64 * 65];
  __shared__ float Msh[64 * 65];
  const int tid = threadIdx.x, l = tid & 63, w = tid >> 6;
  const int bt = blockIdx.x;
  const int b = bt >> 5, t = bt & 31;
  const int lo = l & 15, hi = l >> 4;
  const size_t rb = (size_t)b * LSEQ + t * 64;

  fx4 aK[4], aQ[4];
#pragma unroll
  for (int n = 0; n < 4; ++n) { aK[n] = (fx4){0,0,0,0}; aQ[n] = (fx4){0,0,0,0}; }

  const short* krow = kh + (rb + w * 16 + lo) * D;
  const short* qrow = qh + (rb + w * 16 + lo) * D;
#pragma unroll 2
  for (int ks = 0; ks < 32; ++ks) {
    s16x8 ak = *(const s16x8*)(krow + ks * 32 + hi * 8);
    s16x8 aq = *(const s16x8*)(qrow + ks * 32 + hi * 8);
#pragma unroll
    for (int n = 0; n < 4; ++n) {
      s16x8 bk = *(const s16x8*)(kh + (rb + n * 16 + lo) * D + ks * 32 + hi * 8);
      aK[n] = __builtin_amdgcn_mfma_f32_16x16x32_bf16(ak, bk, aK[n], 0, 0, 0);
      aQ[n] = __builtin_amdgcn_mfma_f32_16x16x32_bf16(aq, bk, aQ[n], 0, 0, 0);
    }
  }
#pragma unroll
  for (int n = 0; n < 4; ++n) {
#pragma unroll
    for (int r = 0; r < 4; ++r) {
      const int i = w * 16 + hi * 4 + r, s = n * 16 + lo;
      const float bi = beta[rb + i];
      Ash[i * 65 + s] = (s < i) ? bi * aK[n][r] : 0.f;
      Tg[(size_t)bt * 4096 + i * 64 + s] = (s <= i) ? f2bf(aQ[n][r]) : (short)0;
    }
  }
  __syncthreads();
  if (w == 0) {
    Msh[0 * 65 + l] = (l == 0) ? 1.f : 0.f;
    for (int i = 1; i < 64; ++i) {
      float s = 0.f;
      for (int ss = 0; ss < i; ++ss) s += Ash[i * 65 + ss] * Msh[ss * 65 + l];
      Msh[i * 65 + l] = ((i == l) ? 1.f : 0.f) - s;
    }
  }
  __syncthreads();
  {
    const int row = tid >> 2, c0 = (tid & 3) * 16;
    s16x8 o0, o1;
#pragma unroll
    for (int j = 0; j < 8; ++j) o0[j] = f2bf(Msh[row * 65 + c0 + j]);
#pragma unroll
    for (int j = 0; j < 8; ++j) o1[j] = f2bf(Msh[row * 65 + c0 + 8 + j]);
    *(s16x8*)(Mg + (size_t)bt * 4096 + row * 64 + c0) = o0;
    *(s16x8*)(Mg + (size_t)bt * 4096 + row * 64 + c0 + 8) = o1;
  }
}

// ---------------------------------------------------------------------------
// Sequential chunked scan (unchanged from round 2).
// ---------------------------------------------------------------------------
__global__ __launch_bounds__(512)
void scan_chunked(const short* __restrict__ qh, const short* __restrict__ kh,
                  const short* __restrict__ vh, const short* __restrict__ kT,
                  const float* __restrict__ beta,
                  const short* __restrict__ Mg, const short* __restrict__ Tg,
                  float* __restrict__ out) {
  __shared__ short SBs[32 * 1024];
  __shared__ short RTs[32 * 64];
  __shared__ short UTs[32 * 64];
  const int tid = threadIdx.x;
  const int l = tid & 63, w = tid >> 6;
  const int b = blockIdx.y, n0 = blockIdx.x * 32;
  const int lo = l & 15, hi = l >> 4;
  const int mR = w >> 1, nR = w & 1;
  const size_t bL = (size_t)b * LSEQ;

  for (int i = tid; i < 32 * 1024 / 2; i += 512) ((int*)SBs)[i] = 0;
  __syncthreads();

  fx4 S[8][2];
#pragma unroll
  for (int mt = 0; mt < 8; ++mt)
#pragma unroll
    for (int nt = 0; nt < 2; ++nt) S[mt][nt] = (fx4){0, 0, 0, 0};

  const int nl = nR * 16 + lo;
  const int c0 = mR * 16 + hi * 4;
  const int swn = (nl & 7) << 4;

  for (int t = 0; t < NCHUNK; ++t) {
    const int r0 = t * 64;
    // ---- P1: R = K_c @ S
    fx4 acc = (fx4){0, 0, 0, 0};
    {
      const short* Arow = kh + (bL + r0 + mR * 16 + lo) * D;
#pragma unroll 4
      for (int ks = 0; ks < 32; ++ks) {
        s16x8 a = *(const s16x8*)(Arow + ks * 32 + hi * 8);
        s16x8 bf = *(const s16x8*)((char*)SBs + (size_t)nl * 2048 +
                                   (((ks * 32 + hi * 8) * 2) ^ swn));
        acc = __builtin_amdgcn_mfma_f32_16x16x32_bf16(a, bf, acc, 0, 0, 0);
      }
    }
    {
      s16x4 pk;
#pragma unroll
      for (int r = 0; r < 4; ++r) {
        const float bv = beta[bL + r0 + c0 + r];
        const float vv = bf2f(((const unsigned short*)vh)[(bL + r0 + c0 + r) * D + n0 + nl]);
        pk[r] = f2bf(bv * (vv - acc[r]));
      }
      *(s16x4*)((char*)RTs + nl * 128 + ((c0 * 2) ^ swn)) = pk;
    }
    __syncthreads();
    // ---- P2: U = Minv @ rhs
    acc = (fx4){0, 0, 0, 0};
    {
      const short* Mrow = Mg + ((size_t)(b * NCHUNK + t)) * 4096 + (mR * 16 + lo) * 64;
#pragma unroll
      for (int ks = 0; ks < 2; ++ks) {
        s16x8 a = *(const s16x8*)(Mrow + ks * 32 + hi * 8);
        s16x8 bf = *(const s16x8*)((char*)RTs + nl * 128 +
                                   (((ks * 32 + hi * 8) * 2) ^ swn));
        acc = __builtin_amdgcn_mfma_f32_16x16x32_bf16(a, bf, acc, 0, 0, 0);
      }
      s16x4 pk;
#pragma unroll
      for (int r = 0; r < 4; ++r) pk[r] = f2bf(acc[r]);
      *(s16x4*)((char*)UTs + nl * 128 + ((c0 * 2) ^ swn)) = pk;
    }
    __syncthreads();
    // ---- P3: O = Q_c @ S + trilQK @ U
    acc = (fx4){0, 0, 0, 0};
    {
      const short* Qrow = qh + (bL + r0 + mR * 16 + lo) * D;
#pragma unroll 4
      for (int ks = 0; ks < 32; ++ks) {
        s16x8 a = *(const s16x8*)(Qrow + ks * 32 + hi * 8);
        s16x8 bf = *(const s16x8*)((char*)SBs + (size_t)nl * 2048 +
                                   (((ks * 32 + hi * 8) * 2) ^ swn));
        acc = __builtin_amdgcn_mfma_f32_16x16x32_bf16(a, bf, acc, 0, 0, 0);
      }
      const short* Trow = Tg + ((size_t)(b * NCHUNK + t)) * 4096 + (mR * 16 + lo) * 64;
#pragma unroll
      for (int ks = 0; ks < 2; ++ks) {
        s16x8 a = *(const s16x8*)(Trow + ks * 32 + hi * 8);
        s16x8 bf = *(const s16x8*)((char*)UTs + nl * 128 +
                                   (((ks * 32 + hi * 8) * 2) ^ swn));
        acc = __builtin_amdgcn_mfma_f32_16x16x32_bf16(a, bf, acc, 0, 0, 0);
      }
#pragma unroll
      for (int r = 0; r < 4; ++r)
        out[(bL + r0 + c0 + r) * D + n0 + nl] = acc[r];
    }
    // ---- P4: S += K_c^T @ U
    {
      s16x8 Bf[2][2];
#pragma unroll
      for (int nt = 0; nt < 2; ++nt) {
        const int nn = nt * 16 + lo;
#pragma unroll
        for (int ks = 0; ks < 2; ++ks)
          Bf[nt][ks] = *(const s16x8*)((char*)UTs + nn * 128 +
                                       (((ks * 32 + hi * 8) * 2) ^ ((nn & 7) << 4)));
      }
#pragma unroll
      for (int mt = 0; mt < 8; ++mt) {
        const short* KTrow = kT + ((size_t)b * D + (w * 8 + mt) * 16 + lo) * LSEQ + r0;
#pragma unroll
        for (int ks = 0; ks < 2; ++ks) {
          s16x8 a = *(const s16x8*)(KTrow + ks * 32 + hi * 8);
#pragma unroll
          for (int nt = 0; nt < 2; ++nt)
            S[mt][nt] = __builtin_amdgcn_mfma_f32_16x16x32_bf16(a, Bf[nt][ks], S[mt][nt], 0, 0, 0);
        }
      }
    }
    __syncthreads();
    // ---- P5: SB refresh = bf16(S)
#pragma unroll
    for (int mt = 0; mt < 8; ++mt)
#pragma unroll
      for (int nt = 0; nt < 2; ++nt) {
        const int nn = nt * 16 + lo;
        const int dk0 = (w * 8 + mt) * 16 + hi * 4;
        s16x4 pk;
#pragma unroll
        for (int r = 0; r < 4; ++r) pk[r] = f2bf(S[mt][nt][r]);
        *(s16x4*)((char*)SBs + (size_t)nn * 2048 + ((dk0 * 2) ^ ((nn & 7) << 4))) = pk;
      }
    __syncthreads();
  }
}

// ---------------------------------------------------------------------------
// LayerNorm in place on out. One wave per row.
// ---------------------------------------------------------------------------
__global__ __launch_bounds__(256)
void ln_kernel(float* __restrict__ o, const float* __restrict__ gamma,
               const float* __restrict__ betap) {
  const int lane = threadIdx.x & 63;
  const int w = threadIdx.x >> 6;
  const size_t row = (size_t)blockIdx.x * 4 + w;
  float4 vals[4];
  float s = 0.f;
#pragma unroll
  for (int m = 0; m < 4; ++m) {
    vals[m] = *(const float4*)&o[row * D + m * 256 + lane * 4];
    s += (vals[m].x + vals[m].y) + (vals[m].z + vals[m].w);
  }
#pragma unroll
  for (int d = 1; d < 64; d <<= 1) s += __shfl_xor(s, d, 64);
  const float mu = s * (1.f / 1024.f);
  float vs = 0.f;
#pragma unroll
  for (int m = 0; m < 4; ++m) {
    float dx = vals[m].x - mu; vs += dx * dx;
    dx = vals[m].y - mu; vs += dx * dx;
    dx = vals[m].z - mu; vs += dx * dx;
    dx = vals[m].w - mu; vs += dx * dx;
  }
#pragma unroll
  for (int d = 1; d < 64; d <<= 1) vs += __shfl_xor(vs, d, 64);
  const float r = 1.f / sqrtf(vs * (1.f / 1024.f) + 1e-5f);
#pragma unroll
  for (int m = 0; m < 4; ++m) {
    const int dbase = m * 256 + lane * 4;
    float4 g4 = *(const float4*)&gamma[dbase];
    float4 b4 = *(const float4*)&betap[dbase];
    float4 y;
    y.x = (vals[m].x - mu) * r * g4.x + b4.x;
    y.y = (vals[m].y - mu) * r * g4.y + b4.y;
    y.z = (vals[m].z - mu) * r * g4.z + b4.z;
    y.w = (vals[m].w - mu) * r * g4.w + b4.w;
    *(float4*)&o[row * D + dbase] = y;
  }
}

// ---------------------------------------------------------------------------
extern "C" void kernel_launch(void* const* d_in, const int* in_sizes, int n_in,
                              void* d_out, int out_size, void* d_ws, size_t ws_size,
                              hipStream_t stream) {
  const float* x   = (const float*)d_in[0];
  const float* Wq  = (const float*)d_in[1];
  const float* Wk  = (const float*)d_in[2];
  const float* Wv  = (const float*)d_in[3];
  const float* Wb  = (const float*)d_in[4];
  const float* lng = (const float*)d_in[5];
  const float* lnb = (const float*)d_in[6];
  float* out = (float*)d_out;

  const size_t MB = 1ull << 20;
  char* wsb = (char*)d_ws;
  float* beta = (float*)wsb;                 // 64 KB
  short* Mg   = (short*)(wsb + 1 * MB);      // 2 MB
  short* Tg   = (short*)(wsb + 4 * MB);      // 2 MB
  short* WTq  = (short*)(wsb + 6 * MB);      // 2 MB
  short* WTk  = (short*)(wsb + 8 * MB);      // 2 MB
  short* WTv  = (short*)(wsb + 10 * MB);     // 2 MB
  short* xh   = (short*)(wsb + 16 * MB);     // 32 MB
  short* qh   = (short*)(wsb + 64 * MB);     // 32 MB
  short* kh   = (short*)(wsb + 96 * MB);
  short* vh   = (short*)(wsb + 128 * MB);
  short* kT   = (short*)(wsb + 160 * MB);

  const int N8 = (BATCH * LSEQ * D) / 8;
  const dim3 pg(128, 8);

  pack_bf16<<<2048, 256, 0, stream>>>(x, xh, N8);
  wtrans<<<dim3(16, 16), 256, 0, stream>>>(Wq, WTq);
  wtrans<<<dim3(16, 16), 256, 0, stream>>>(Wk, WTk);
  wtrans<<<dim3(16, 16), 256, 0, stream>>>(Wv, WTv);

  proj_mfma<<<pg, 256, 0, stream>>>(xh, WTq, qh, 0, 0.03125f);
  proj_mfma<<<pg, 256, 0, stream>>>(xh, WTk, kh, 1, 1.f);
  proj_mfma<<<pg, 256, 0, stream>>>(xh, WTv, vh, 2, 1.f);

  knormb<<<4096, 256, 0, stream>>>(kh);
  transpose_bf16<<<dim3(16, 32, 8), 256, 0, stream>>>(kh, kT);
  beta_kernel<<<4096, 256, 0, stream>>>(x, Wb, beta);

  precompute<<<256, 256, 0, stream>>>(qh, kh, beta, Mg, Tg);
  scan_chunked<<<dim3(32, 8), 512, 0, stream>>>(qh, kh, vh, kT, beta, Mg, Tg, out);
  ln_kernel<<<4096, 256, 0, stream>>>(out, lng, lnb);
}